// Round 21
// baseline (525.847 us; speedup 1.0000x reference)
//
#include <hip/hip_runtime.h>
#include <hip/hip_fp16.h>
#include <math.h>

#define NN 100000
#define NE 800000
#define ET (NN + NE)   /* 900000 edges incl self-loops */
#define NG 256
#define SLOPE 0.2f
#define LOG2E 1.44269504088896340736f
#define NB1 ((NN + 255) / 256)   /* 391 scan blocks */
#define NRT 6250                 /* 100000/16 row tiles */
#define NBH ((ET + 255) / 256)   /* 3516 hist blocks */

typedef _Float16 f16x2 __attribute__((ext_vector_type(2)));
typedef _Float16 f16x8 __attribute__((ext_vector_type(8)));
typedef float    f32x4 __attribute__((ext_vector_type(4)));

__device__ __forceinline__ void unpack8(float4 raw, float* x) {
    const __half2* hp = (const __half2*)&raw;
    #pragma unroll
    for (int j = 0; j < 4; ++j) {
        float2 f = __half22float2(hp[j]);
        x[2 * j] = f.x; x[2 * j + 1] = f.y;
    }
}
__device__ __forceinline__ void unpack4(float2 raw, float* x) {
    const __half2* hp = (const __half2*)&raw;
    #pragma unroll
    for (int j = 0; j < 2; ++j) {
        float2 f = __half22float2(hp[j]);
        x[2 * j] = f.x; x[2 * j + 1] = f.y;
    }
}

// ---- W fragment pack body (device): f32 [K][MHALF] Wl|Wr -> hi/lo fp16 ----
template<int K, int MHALF>
__device__ __forceinline__ void packW_body(int idx,
                                           const float* __restrict__ Wl,
                                           const float* __restrict__ Wr,
                                           __half* __restrict__ hi, __half* __restrict__ lo)
{
    constexpr int KS = K / 32;
    const int i   = idx & 7;
    const int l   = (idx >> 3) & 63;
    const int rem = idx >> 9;
    const int ks  = rem % KS;
    const int ct  = rem / KS;
    const int k   = ks * 32 + (l >> 4) * 8 + i;
    const int col = ct * 16 + (l & 15);
    const float w = (col < MHALF) ? Wl[(size_t)k * MHALF + col]
                                  : Wr[(size_t)k * MHALF + (col - MHALF)];
    const __half h = __float2half(w);
    hi[idx] = h;
    lo[idx] = __float2half(w - __half2float(h));
}

// ---- fused init: packW1 (blocks 0..63) | packW2 (64..95) | hist (96..) ----
__global__ void init_kernel(const float* __restrict__ Wl1, const float* __restrict__ Wr1,
                            __half* __restrict__ whi1, __half* __restrict__ wlo1,
                            const float* __restrict__ Wl2, const float* __restrict__ Wr2,
                            __half* __restrict__ whi2, __half* __restrict__ wlo2,
                            const int* __restrict__ edst, int* __restrict__ deg)
{
    const int b = blockIdx.x;
    if (b < 64) {
        packW_body<64, 128>(b * 256 + threadIdx.x, Wl1, Wr1, whi1, wlo1);   // 16384 elems
    } else if (b < 96) {
        packW_body<128, 32>((b - 64) * 256 + threadIdx.x, Wl2, Wr2, whi2, wlo2); // 8192
    } else {
        const int e = (b - 96) * 256 + threadIdx.x;
        if (e < ET) {
            int d = (e < NE) ? edst[e] : (e - NE);
            atomicAdd(deg + d, 1);
        }
    }
}

// ---- transform 1 via MFMA ----
__global__ __launch_bounds__(256, 4)
void t1_mfma_kernel(const float* __restrict__ X,
                    const __half* __restrict__ Whi, const __half* __restrict__ Wlo,
                    const float* __restrict__ bl, const float* __restrict__ br,
                    __half* __restrict__ XLh, __half* __restrict__ XRh)
{
    const int rt = blockIdx.x * 4 + (threadIdx.x >> 6);
    if (rt >= NRT) return;
    const int l = threadIdx.x & 63;
    const int row_a = rt * 16 + (l & 15);
    const int kbase = (l >> 4) * 8;

    f16x8 a[2];
    #pragma unroll
    for (int ks = 0; ks < 2; ++ks) {
        const float4 x0 = *(const float4*)(X + (size_t)row_a * 64 + ks * 32 + kbase);
        const float4 x1 = *(const float4*)(X + (size_t)row_a * 64 + ks * 32 + kbase + 4);
        a[ks][0] = (_Float16)x0.x; a[ks][1] = (_Float16)x0.y;
        a[ks][2] = (_Float16)x0.z; a[ks][3] = (_Float16)x0.w;
        a[ks][4] = (_Float16)x1.x; a[ks][5] = (_Float16)x1.y;
        a[ks][6] = (_Float16)x1.z; a[ks][7] = (_Float16)x1.w;
    }

    for (int ct = 0; ct < 16; ++ct) {
        f32x4 acc = {0.f, 0.f, 0.f, 0.f};
        #pragma unroll
        for (int ks = 0; ks < 2; ++ks) {
            const f16x8 bh = *(const f16x8*)(Whi + ((size_t)(ct * 2 + ks) * 64 + l) * 8);
            const f16x8 bL = *(const f16x8*)(Wlo + ((size_t)(ct * 2 + ks) * 64 + l) * 8);
            acc = __builtin_amdgcn_mfma_f32_16x16x32_f16(a[ks], bh, acc, 0, 0, 0);
            acc = __builtin_amdgcn_mfma_f32_16x16x32_f16(a[ks], bL, acc, 0, 0, 0);
        }
        const int col = ct * 16 + (l & 15);
        const float bias = (col < 128) ? bl[col] : br[col - 128];
        __half* const dst = (col < 128) ? XLh : XRh;
        const int dcol = col & 127;
        #pragma unroll
        for (int r = 0; r < 4; ++r) {
            const int row = rt * 16 + (l >> 4) * 4 + r;
            dst[(size_t)row * 128 + dcol] = __float2half(acc[r] + bias);
        }
    }
}

// ---- transform 2 via MFMA ----
__global__ __launch_bounds__(256, 4)
void t2_mfma_kernel(const __half* __restrict__ H1h,
                    const __half* __restrict__ Whi, const __half* __restrict__ Wlo,
                    const float* __restrict__ bl, const float* __restrict__ br,
                    __half* __restrict__ XLh, __half* __restrict__ XRh)
{
    const int rt = blockIdx.x * 4 + (threadIdx.x >> 6);
    if (rt >= NRT) return;
    const int l = threadIdx.x & 63;
    const int row_a = rt * 16 + (l & 15);
    const int kbase = (l >> 4) * 8;

    f16x8 a[4];
    #pragma unroll
    for (int ks = 0; ks < 4; ++ks)
        a[ks] = *(const f16x8*)(H1h + (size_t)row_a * 128 + ks * 32 + kbase);

    for (int ct = 0; ct < 4; ++ct) {
        f32x4 acc = {0.f, 0.f, 0.f, 0.f};
        #pragma unroll
        for (int ks = 0; ks < 4; ++ks) {
            const f16x8 bh = *(const f16x8*)(Whi + ((size_t)(ct * 4 + ks) * 64 + l) * 8);
            const f16x8 bL = *(const f16x8*)(Wlo + ((size_t)(ct * 4 + ks) * 64 + l) * 8);
            acc = __builtin_amdgcn_mfma_f32_16x16x32_f16(a[ks], bh, acc, 0, 0, 0);
            acc = __builtin_amdgcn_mfma_f32_16x16x32_f16(a[ks], bL, acc, 0, 0, 0);
        }
        const int col = ct * 16 + (l & 15);
        const float bias = (col < 32) ? bl[col] : br[col - 32];
        __half* const dst = (col < 32) ? XLh : XRh;
        const int dcol = col & 31;
        #pragma unroll
        for (int r = 0; r < 4; ++r) {
            const int row = rt * 16 + (l >> 4) * 4 + r;
            dst[(size_t)row * 32 + dcol] = __float2half(acc[r] + bias);
        }
    }
}

// ---- 3-kernel exclusive scan ----
__global__ void scan1_kernel(const int* __restrict__ deg, int* __restrict__ rowstart,
                             int* __restrict__ bsum)
{
    __shared__ int lds[256];
    int t = threadIdx.x, idx = blockIdx.x * 256 + t;
    int v = (idx < NN) ? deg[idx] : 0;
    lds[t] = v;
    __syncthreads();
    #pragma unroll
    for (int off = 1; off < 256; off <<= 1) {
        int add = (t >= off) ? lds[t - off] : 0;
        __syncthreads();
        lds[t] += add;
        __syncthreads();
    }
    if (idx < NN) rowstart[idx + 1] = lds[t];
    if (t == 255) bsum[blockIdx.x] = lds[255];
}

__global__ void scan2_kernel(int* __restrict__ bsum)
{
    __shared__ int lds[512];
    int t = threadIdx.x;
    int v = (t < NB1) ? bsum[t] : 0;
    lds[t] = v;
    __syncthreads();
    #pragma unroll
    for (int off = 1; off < 512; off <<= 1) {
        int add = (t >= off) ? lds[t - off] : 0;
        __syncthreads();
        lds[t] += add;
        __syncthreads();
    }
    if (t < NB1) bsum[t] = lds[t] - v;
}

__global__ void scan3_kernel(int* __restrict__ rowstart, const int* __restrict__ bsum)
{
    int idx = blockIdx.x * 256 + threadIdx.x;
    if (idx == 0) rowstart[0] = 0;
    if (idx < NN) rowstart[idx + 1] += bsum[blockIdx.x];
}

// ---- CSR scatter (separate pre-zeroed cursor) ----
__global__ void scatter_kernel(const int* __restrict__ esrc, const int* __restrict__ edst,
                               const int* __restrict__ rowstart,
                               int* __restrict__ cursor, int* __restrict__ csr_src)
{
    int e = blockIdx.x * 256 + threadIdx.x;
    if (e >= ET) return;
    int s, d;
    if (e < NE) { s = esrc[e]; d = edst[e]; } else { s = e - NE; d = s; }
    int pos = rowstart[d] + atomicAdd(cursor + d, 1);
    csr_src[pos] = s;
}

// ---- layer 1 fused GATv2 (H=4, C=32): wave/node, 4 edge-slots, pipelined ----
__global__ void gat1_kernel(const int* __restrict__ rowstart, const int* __restrict__ csr_src,
                            const __half* __restrict__ XLh, const __half* __restrict__ XRh,
                            const float* __restrict__ att, const float* __restrict__ bias,
                            __half* __restrict__ H1h)
{
    const int node = blockIdx.x * 4 + (threadIdx.x >> 6);
    if (node >= NN) return;
    const int lane = threadIdx.x & 63;
    const int slot = lane >> 4;
    const int q    = lane & 15;
    const int c0   = q * 8;

    float4 xr_raw = *(const float4*)(XRh + (size_t)node * 128 + c0);
    const f16x2* xrh = (const f16x2*)&xr_raw;
    f16x2 ath[4];
    {
        const float4 a0 = *(const float4*)(att + c0);
        const float4 a1 = *(const float4*)(att + c0 + 4);
        ath[0] = (f16x2){(_Float16)(a0.x * LOG2E), (_Float16)(a0.y * LOG2E)};
        ath[1] = (f16x2){(_Float16)(a0.z * LOG2E), (_Float16)(a0.w * LOG2E)};
        ath[2] = (f16x2){(_Float16)(a1.x * LOG2E), (_Float16)(a1.y * LOG2E)};
        ath[3] = (f16x2){(_Float16)(a1.z * LOG2E), (_Float16)(a1.w * LOG2E)};
    }
    const f16x2 s2 = {(_Float16)SLOPE, (_Float16)SLOPE};
    const int beg = rowstart[node], end = rowstart[node + 1];
    float m = -INFINITY, ssum = 0.f;
    float acc[8] = {0.f, 0.f, 0.f, 0.f, 0.f, 0.f, 0.f, 0.f};

    bool valid = (beg + slot) < end;
    int s = valid ? csr_src[beg + slot] : 0;
    float4 cur = *(const float4*)(XLh + (size_t)s * 128 + c0);

    for (int i = beg; i < end; i += 4) {
        const int nidx    = i + 4 + slot;
        const bool nvalid = nidx < end;
        const int ns      = nvalid ? csr_src[nidx] : 0;
        const float4 nxt  = *(const float4*)(XLh + (size_t)ns * 128 + c0);

        const f16x2* xlh = (const f16x2*)&cur;
        float p = 0.f;
        #pragma unroll
        for (int j = 0; j < 4; ++j) {
            f16x2 v  = xlh[j] + xrh[j];
            f16x2 lv = __builtin_elementwise_max(v, s2 * v);
            p = __builtin_amdgcn_fdot2(lv, ath[j], p, false);
        }
        p += __shfl_xor(p, 1);
        p += __shfl_xor(p, 2);
        if (!valid) p = -INFINITY;
        float pm = fmaxf(p, __shfl_xor(p, 16));
        pm = fmaxf(pm, __shfl_xor(pm, 32));
        if (__any(pm > m + 8.f)) {
            const float mn = fmaxf(m, pm);
            const float sc = exp2f(m - mn);
            ssum *= sc;
            #pragma unroll
            for (int j = 0; j < 8; ++j) acc[j] *= sc;
            m = mn;
        }
        const float e = exp2f(p - m);
        ssum += e;
        float xlf[8];
        unpack8(cur, xlf);
        #pragma unroll
        for (int j = 0; j < 8; ++j)
            acc[j] = fmaf(e, xlf[j], acc[j]);

        cur = nxt;
        valid = nvalid;
    }
    ssum += __shfl_xor(ssum, 16);
    ssum += __shfl_xor(ssum, 32);
    #pragma unroll
    for (int j = 0; j < 8; ++j) {
        acc[j] += __shfl_xor(acc[j], 16);
        acc[j] += __shfl_xor(acc[j], 32);
    }
    if (slot == 0) {
        const float inv = 1.f / (ssum + 1e-16f);
        const float4 b0 = *(const float4*)(bias + c0);
        const float4 b1 = *(const float4*)(bias + c0 + 4);
        const float bb[8] = {b0.x, b0.y, b0.z, b0.w, b1.x, b1.y, b1.z, b1.w};
        __half2 outh[4];
        #pragma unroll
        for (int j = 0; j < 4; ++j) {
            float o0 = acc[2 * j] * inv + bb[2 * j];
            float o1 = acc[2 * j + 1] * inv + bb[2 * j + 1];
            o0 = o0 > 0.f ? o0 : expm1f(o0);
            o1 = o1 > 0.f ? o1 : expm1f(o1);
            outh[j] = __float22half2_rn(make_float2(o0, o1));
        }
        *(float4*)(H1h + (size_t)node * 128 + c0) = *(const float4*)outh;
    }
}

// ---- layer 2 fused GATv2 + pool (H=1, C=32): 32 lanes/node, 4 slots, pipelined.
// Epilogue accumulates (o+bias2) directly into pool (L2-resident atomics) —
// h2 buffer and pool_kernel eliminated. ----
__global__ void gat2_kernel(const int* __restrict__ rowstart, const int* __restrict__ csr_src,
                            const __half* __restrict__ XLh, const __half* __restrict__ XRh,
                            const float* __restrict__ att, const float* __restrict__ bias2,
                            const int* __restrict__ batch,
                            float* __restrict__ pool, float* __restrict__ cnt)
{
    const int node = blockIdx.x * 8 + (threadIdx.x >> 5);
    if (node >= NN) return;
    const int l2   = threadIdx.x & 31;
    const int slot = l2 >> 3;
    const int q    = l2 & 7;
    const int c0   = q * 4;

    float2 xr_raw = *(const float2*)(XRh + (size_t)node * 32 + c0);
    const f16x2* xrh = (const f16x2*)&xr_raw;
    f16x2 ath[2];
    {
        const float4 a = *(const float4*)(att + c0);
        ath[0] = (f16x2){(_Float16)(a.x * LOG2E), (_Float16)(a.y * LOG2E)};
        ath[1] = (f16x2){(_Float16)(a.z * LOG2E), (_Float16)(a.w * LOG2E)};
    }
    const f16x2 s2 = {(_Float16)SLOPE, (_Float16)SLOPE};
    const int beg = rowstart[node], end = rowstart[node + 1];
    float m = -INFINITY, ssum = 0.f;
    float acc[4] = {0.f, 0.f, 0.f, 0.f};

    bool valid = (beg + slot) < end;
    int s = valid ? csr_src[beg + slot] : 0;
    float2 cur = *(const float2*)(XLh + (size_t)s * 32 + c0);

    for (int i = beg; i < end; i += 4) {
        const int nidx    = i + 4 + slot;
        const bool nvalid = nidx < end;
        const int ns      = nvalid ? csr_src[nidx] : 0;
        const float2 nxt  = *(const float2*)(XLh + (size_t)ns * 32 + c0);

        const f16x2* xlh = (const f16x2*)&cur;
        float p = 0.f;
        #pragma unroll
        for (int j = 0; j < 2; ++j) {
            f16x2 v  = xlh[j] + xrh[j];
            f16x2 lv = __builtin_elementwise_max(v, s2 * v);
            p = __builtin_amdgcn_fdot2(lv, ath[j], p, false);
        }
        p += __shfl_xor(p, 1);
        p += __shfl_xor(p, 2);
        p += __shfl_xor(p, 4);
        if (!valid) p = -INFINITY;
        float pm = fmaxf(p, __shfl_xor(p, 8));
        pm = fmaxf(pm, __shfl_xor(pm, 16));
        if (__any(pm > m + 8.f)) {
            const float mn = fmaxf(m, pm);
            const float sc = exp2f(m - mn);
            ssum *= sc;
            #pragma unroll
            for (int j = 0; j < 4; ++j) acc[j] *= sc;
            m = mn;
        }
        const float e = exp2f(p - m);
        ssum += e;
        float xlf[4];
        unpack4(cur, xlf);
        #pragma unroll
        for (int j = 0; j < 4; ++j)
            acc[j] = fmaf(e, xlf[j], acc[j]);

        cur = nxt;
        valid = nvalid;
    }
    ssum += __shfl_xor(ssum, 8);
    ssum += __shfl_xor(ssum, 16);
    #pragma unroll
    for (int j = 0; j < 4; ++j) {
        acc[j] += __shfl_xor(acc[j], 8);
        acc[j] += __shfl_xor(acc[j], 16);
    }
    if (slot == 0) {                       // 8 lanes (q=0..7) cover 32 cols
        const float inv = 1.f / (ssum + 1e-16f);
        const int g = batch[node];
        #pragma unroll
        for (int j = 0; j < 4; ++j)
            atomicAdd(pool + (size_t)g * 32 + c0 + j, acc[j] * inv + bias2[c0 + j]);
        if (q == 0) atomicAdd(cnt + g, 1.f);
    }
}

// ---- per-graph head MLP ----
__global__ void head_kernel(const float* __restrict__ pool, const float* __restrict__ cnt,
                            const float* __restrict__ Wh1, const float* __restrict__ bh1,
                            const float* __restrict__ Wh2, const float* __restrict__ bh2,
                            float* __restrict__ out)
{
    int g = blockIdx.x;
    int c = threadIdx.x;      // 0..63
    float partial = 0.f;
    if (c < 32) {
        float invc = 1.f / fmaxf(cnt[g], 1.f);
        float acc = bh1[c];
        #pragma unroll
        for (int k = 0; k < 32; ++k)
            acc = fmaf(pool[g * 32 + k] * invc, Wh1[k * 32 + c], acc);
        float z = fmaxf(acc, 0.f);
        partial = z * Wh2[c];
    }
    #pragma unroll
    for (int off = 32; off >= 1; off >>= 1)
        partial += __shfl_down(partial, off);
    if (c == 0) out[g] = partial + bh2[0];
}

extern "C" void kernel_launch(void* const* d_in, const int* in_sizes, int n_in,
                              void* d_out, int out_size, void* d_ws, size_t ws_size,
                              hipStream_t stream)
{
    const float* x     = (const float*)d_in[0];
    const int*   ei    = (const int*)d_in[1];
    const int*   batch = (const int*)d_in[2];
    const float* Wl1   = (const float*)d_in[3];
    const float* bl1   = (const float*)d_in[4];
    const float* Wr1   = (const float*)d_in[5];
    const float* br1   = (const float*)d_in[6];
    const float* att1  = (const float*)d_in[7];
    const float* bias1 = (const float*)d_in[8];
    const float* Wl2   = (const float*)d_in[9];
    const float* bl2   = (const float*)d_in[10];
    const float* Wr2   = (const float*)d_in[11];
    const float* br2   = (const float*)d_in[12];
    const float* att2  = (const float*)d_in[13];
    const float* bias2 = (const float*)d_in[14];
    const float* Wh1   = (const float*)d_in[15];
    const float* bh1   = (const float*)d_in[16];
    const float* Wh2   = (const float*)d_in[17];
    const float* bh2   = (const float*)d_in[18];
    const int* esrc = ei;
    const int* edst = ei + NE;

    // ---- workspace layout (bytes) ----
    char* wsb = (char*)d_ws;
    __half* xl1h = (__half*)wsb;                               // NN*128*2
    __half* xr1h = (__half*)(wsb + (size_t)NN * 128 * 2);      // NN*128*2
    __half* h1h  = xr1h;                                       // alias (per-row RAW in-wave)
    char* p2 = wsb + (size_t)NN * 128 * 4;
    __half* xl2h = (__half*)p2;                                // NN*32*2
    __half* xr2h = (__half*)(p2 + (size_t)NN * 32 * 2);        // NN*32*2
    // zero-region: deg | cursor | pool | cnt  (single memset)
    int*    zr     = (int*)(p2 + (size_t)NN * 32 * 4);
    int*    deg    = zr;                                       // NN
    int*    cursor = zr + NN;                                  // NN
    float*  pool   = (float*)(zr + 2 * NN);                    // NG*32
    float*  cnt    = pool + (size_t)NG * 32;                   // NG
    int* rowstart  = (int*)(cnt + NG);                         // NN+1
    int* bsum      = rowstart + NN + 1;                        // 512
    int* csr_src   = bsum + 512;                               // ET
    __half* whi1   = (__half*)(csr_src + ET);                  // 16384
    __half* wlo1   = whi1 + 16384;
    __half* whi2   = wlo1 + 16384;                             // 8192
    __half* wlo2   = whi2 + 8192;

    // ---- single memset + fused init (packW1|packW2|hist) + scan + scatter ----
    hipMemsetAsync(zr, 0, (size_t)(2 * NN + NG * 32 + NG) * sizeof(int), stream);
    init_kernel<<<96 + NBH, 256, 0, stream>>>(Wl1, Wr1, whi1, wlo1,
                                              Wl2, Wr2, whi2, wlo2, edst, deg);
    scan1_kernel<<<NB1, 256, 0, stream>>>(deg, rowstart, bsum);
    scan2_kernel<<<1, 512, 0, stream>>>(bsum);
    scan3_kernel<<<NB1, 256, 0, stream>>>(rowstart, bsum);
    scatter_kernel<<<(ET + 255) / 256, 256, 0, stream>>>(esrc, edst, rowstart, cursor, csr_src);

    // ---- layer 1 ----
    t1_mfma_kernel<<<(NRT + 3) / 4, 256, 0, stream>>>(
        x, whi1, wlo1, bl1, br1, xl1h, xr1h);
    gat1_kernel<<<(NN + 3) / 4, 256, 0, stream>>>(
        rowstart, csr_src, xl1h, xr1h, att1, bias1, h1h);

    // ---- layer 2 (pool fused into gat2 epilogue) ----
    t2_mfma_kernel<<<(NRT + 3) / 4, 256, 0, stream>>>(
        h1h, whi2, wlo2, bl2, br2, xl2h, xr2h);
    gat2_kernel<<<(NN + 7) / 8, 256, 0, stream>>>(
        rowstart, csr_src, xl2h, xr2h, att2, bias2, batch, pool, cnt);

    // ---- head ----
    head_kernel<<<NG, 64, 0, stream>>>(pool, cnt, Wh1, bh1, Wh2, bh2, (float*)d_out);
}

// Round 22
// 258.787 us; speedup vs baseline: 2.0320x; 2.0320x over previous
//
#include <hip/hip_runtime.h>
#include <hip/hip_fp16.h>
#include <math.h>

#define NN 100000
#define NE 800000
#define ET (NN + NE)   /* 900000 edges incl self-loops */
#define NG 256
#define SLOPE 0.2f
#define LOG2E 1.44269504088896340736f
#define NB1 ((NN + 255) / 256)   /* 391 scan blocks */
#define NRT 6250                 /* 100000/16 row tiles */
#define NBH ((ET + 255) / 256)   /* 3516 hist blocks */

typedef _Float16 f16x2 __attribute__((ext_vector_type(2)));
typedef _Float16 f16x8 __attribute__((ext_vector_type(8)));
typedef float    f32x4 __attribute__((ext_vector_type(4)));

__device__ __forceinline__ void unpack8(float4 raw, float* x) {
    const __half2* hp = (const __half2*)&raw;
    #pragma unroll
    for (int j = 0; j < 4; ++j) {
        float2 f = __half22float2(hp[j]);
        x[2 * j] = f.x; x[2 * j + 1] = f.y;
    }
}
__device__ __forceinline__ void unpack4(float2 raw, float* x) {
    const __half2* hp = (const __half2*)&raw;
    #pragma unroll
    for (int j = 0; j < 2; ++j) {
        float2 f = __half22float2(hp[j]);
        x[2 * j] = f.x; x[2 * j + 1] = f.y;
    }
}

// ---- W fragment pack body (device): f32 [K][MHALF] Wl|Wr -> hi/lo fp16 ----
template<int K, int MHALF>
__device__ __forceinline__ void packW_body(int idx,
                                           const float* __restrict__ Wl,
                                           const float* __restrict__ Wr,
                                           __half* __restrict__ hi, __half* __restrict__ lo)
{
    constexpr int KS = K / 32;
    const int i   = idx & 7;
    const int l   = (idx >> 3) & 63;
    const int rem = idx >> 9;
    const int ks  = rem % KS;
    const int ct  = rem / KS;
    const int k   = ks * 32 + (l >> 4) * 8 + i;
    const int col = ct * 16 + (l & 15);
    const float w = (col < MHALF) ? Wl[(size_t)k * MHALF + col]
                                  : Wr[(size_t)k * MHALF + (col - MHALF)];
    const __half h = __float2half(w);
    hi[idx] = h;
    lo[idx] = __float2half(w - __half2float(h));
}

// ---- fused init: packW1 (blocks 0..63) | packW2 (64..95) | hist (96..) ----
__global__ void init_kernel(const float* __restrict__ Wl1, const float* __restrict__ Wr1,
                            __half* __restrict__ whi1, __half* __restrict__ wlo1,
                            const float* __restrict__ Wl2, const float* __restrict__ Wr2,
                            __half* __restrict__ whi2, __half* __restrict__ wlo2,
                            const int* __restrict__ edst, int* __restrict__ deg)
{
    const int b = blockIdx.x;
    if (b < 64) {
        packW_body<64, 128>(b * 256 + threadIdx.x, Wl1, Wr1, whi1, wlo1);   // 16384 elems
    } else if (b < 96) {
        packW_body<128, 32>((b - 64) * 256 + threadIdx.x, Wl2, Wr2, whi2, wlo2); // 8192
    } else {
        const int e = (b - 96) * 256 + threadIdx.x;
        if (e < ET) {
            int d = (e < NE) ? edst[e] : (e - NE);
            atomicAdd(deg + d, 1);
        }
    }
}

// ---- transform 1 via MFMA ----
__global__ __launch_bounds__(256, 4)
void t1_mfma_kernel(const float* __restrict__ X,
                    const __half* __restrict__ Whi, const __half* __restrict__ Wlo,
                    const float* __restrict__ bl, const float* __restrict__ br,
                    __half* __restrict__ XLh, __half* __restrict__ XRh)
{
    const int rt = blockIdx.x * 4 + (threadIdx.x >> 6);
    if (rt >= NRT) return;
    const int l = threadIdx.x & 63;
    const int row_a = rt * 16 + (l & 15);
    const int kbase = (l >> 4) * 8;

    f16x8 a[2];
    #pragma unroll
    for (int ks = 0; ks < 2; ++ks) {
        const float4 x0 = *(const float4*)(X + (size_t)row_a * 64 + ks * 32 + kbase);
        const float4 x1 = *(const float4*)(X + (size_t)row_a * 64 + ks * 32 + kbase + 4);
        a[ks][0] = (_Float16)x0.x; a[ks][1] = (_Float16)x0.y;
        a[ks][2] = (_Float16)x0.z; a[ks][3] = (_Float16)x0.w;
        a[ks][4] = (_Float16)x1.x; a[ks][5] = (_Float16)x1.y;
        a[ks][6] = (_Float16)x1.z; a[ks][7] = (_Float16)x1.w;
    }

    for (int ct = 0; ct < 16; ++ct) {
        f32x4 acc = {0.f, 0.f, 0.f, 0.f};
        #pragma unroll
        for (int ks = 0; ks < 2; ++ks) {
            const f16x8 bh = *(const f16x8*)(Whi + ((size_t)(ct * 2 + ks) * 64 + l) * 8);
            const f16x8 bL = *(const f16x8*)(Wlo + ((size_t)(ct * 2 + ks) * 64 + l) * 8);
            acc = __builtin_amdgcn_mfma_f32_16x16x32_f16(a[ks], bh, acc, 0, 0, 0);
            acc = __builtin_amdgcn_mfma_f32_16x16x32_f16(a[ks], bL, acc, 0, 0, 0);
        }
        const int col = ct * 16 + (l & 15);
        const float bias = (col < 128) ? bl[col] : br[col - 128];
        __half* const dst = (col < 128) ? XLh : XRh;
        const int dcol = col & 127;
        #pragma unroll
        for (int r = 0; r < 4; ++r) {
            const int row = rt * 16 + (l >> 4) * 4 + r;
            dst[(size_t)row * 128 + dcol] = __float2half(acc[r] + bias);
        }
    }
}

// ---- transform 2 via MFMA ----
__global__ __launch_bounds__(256, 4)
void t2_mfma_kernel(const __half* __restrict__ H1h,
                    const __half* __restrict__ Whi, const __half* __restrict__ Wlo,
                    const float* __restrict__ bl, const float* __restrict__ br,
                    __half* __restrict__ XLh, __half* __restrict__ XRh)
{
    const int rt = blockIdx.x * 4 + (threadIdx.x >> 6);
    if (rt >= NRT) return;
    const int l = threadIdx.x & 63;
    const int row_a = rt * 16 + (l & 15);
    const int kbase = (l >> 4) * 8;

    f16x8 a[4];
    #pragma unroll
    for (int ks = 0; ks < 4; ++ks)
        a[ks] = *(const f16x8*)(H1h + (size_t)row_a * 128 + ks * 32 + kbase);

    for (int ct = 0; ct < 4; ++ct) {
        f32x4 acc = {0.f, 0.f, 0.f, 0.f};
        #pragma unroll
        for (int ks = 0; ks < 4; ++ks) {
            const f16x8 bh = *(const f16x8*)(Whi + ((size_t)(ct * 4 + ks) * 64 + l) * 8);
            const f16x8 bL = *(const f16x8*)(Wlo + ((size_t)(ct * 4 + ks) * 64 + l) * 8);
            acc = __builtin_amdgcn_mfma_f32_16x16x32_f16(a[ks], bh, acc, 0, 0, 0);
            acc = __builtin_amdgcn_mfma_f32_16x16x32_f16(a[ks], bL, acc, 0, 0, 0);
        }
        const int col = ct * 16 + (l & 15);
        const float bias = (col < 32) ? bl[col] : br[col - 32];
        __half* const dst = (col < 32) ? XLh : XRh;
        const int dcol = col & 31;
        #pragma unroll
        for (int r = 0; r < 4; ++r) {
            const int row = rt * 16 + (l >> 4) * 4 + r;
            dst[(size_t)row * 32 + dcol] = __float2half(acc[r] + bias);
        }
    }
}

// ---- 3-kernel exclusive scan ----
__global__ void scan1_kernel(const int* __restrict__ deg, int* __restrict__ rowstart,
                             int* __restrict__ bsum)
{
    __shared__ int lds[256];
    int t = threadIdx.x, idx = blockIdx.x * 256 + t;
    int v = (idx < NN) ? deg[idx] : 0;
    lds[t] = v;
    __syncthreads();
    #pragma unroll
    for (int off = 1; off < 256; off <<= 1) {
        int add = (t >= off) ? lds[t - off] : 0;
        __syncthreads();
        lds[t] += add;
        __syncthreads();
    }
    if (idx < NN) rowstart[idx + 1] = lds[t];
    if (t == 255) bsum[blockIdx.x] = lds[255];
}

__global__ void scan2_kernel(int* __restrict__ bsum)
{
    __shared__ int lds[512];
    int t = threadIdx.x;
    int v = (t < NB1) ? bsum[t] : 0;
    lds[t] = v;
    __syncthreads();
    #pragma unroll
    for (int off = 1; off < 512; off <<= 1) {
        int add = (t >= off) ? lds[t - off] : 0;
        __syncthreads();
        lds[t] += add;
        __syncthreads();
    }
    if (t < NB1) bsum[t] = lds[t] - v;
}

__global__ void scan3_kernel(int* __restrict__ rowstart, const int* __restrict__ bsum)
{
    int idx = blockIdx.x * 256 + threadIdx.x;
    if (idx == 0) rowstart[0] = 0;
    if (idx < NN) rowstart[idx + 1] += bsum[blockIdx.x];
}

// ---- CSR scatter (separate pre-zeroed cursor) ----
__global__ void scatter_kernel(const int* __restrict__ esrc, const int* __restrict__ edst,
                               const int* __restrict__ rowstart,
                               int* __restrict__ cursor, int* __restrict__ csr_src)
{
    int e = blockIdx.x * 256 + threadIdx.x;
    if (e >= ET) return;
    int s, d;
    if (e < NE) { s = esrc[e]; d = edst[e]; } else { s = e - NE; d = s; }
    int pos = rowstart[d] + atomicAdd(cursor + d, 1);
    csr_src[pos] = s;
}

// ---- layer 1 fused GATv2 (H=4, C=32): wave/node, 4 edge-slots, pipelined ----
__global__ void gat1_kernel(const int* __restrict__ rowstart, const int* __restrict__ csr_src,
                            const __half* __restrict__ XLh, const __half* __restrict__ XRh,
                            const float* __restrict__ att, const float* __restrict__ bias,
                            __half* __restrict__ H1h)
{
    const int node = blockIdx.x * 4 + (threadIdx.x >> 6);
    if (node >= NN) return;
    const int lane = threadIdx.x & 63;
    const int slot = lane >> 4;
    const int q    = lane & 15;
    const int c0   = q * 8;

    float4 xr_raw = *(const float4*)(XRh + (size_t)node * 128 + c0);
    const f16x2* xrh = (const f16x2*)&xr_raw;
    f16x2 ath[4];
    {
        const float4 a0 = *(const float4*)(att + c0);
        const float4 a1 = *(const float4*)(att + c0 + 4);
        ath[0] = (f16x2){(_Float16)(a0.x * LOG2E), (_Float16)(a0.y * LOG2E)};
        ath[1] = (f16x2){(_Float16)(a0.z * LOG2E), (_Float16)(a0.w * LOG2E)};
        ath[2] = (f16x2){(_Float16)(a1.x * LOG2E), (_Float16)(a1.y * LOG2E)};
        ath[3] = (f16x2){(_Float16)(a1.z * LOG2E), (_Float16)(a1.w * LOG2E)};
    }
    const f16x2 s2 = {(_Float16)SLOPE, (_Float16)SLOPE};
    const int beg = rowstart[node], end = rowstart[node + 1];
    float m = -INFINITY, ssum = 0.f;
    float acc[8] = {0.f, 0.f, 0.f, 0.f, 0.f, 0.f, 0.f, 0.f};

    bool valid = (beg + slot) < end;
    int s = valid ? csr_src[beg + slot] : 0;
    float4 cur = *(const float4*)(XLh + (size_t)s * 128 + c0);

    for (int i = beg; i < end; i += 4) {
        const int nidx    = i + 4 + slot;
        const bool nvalid = nidx < end;
        const int ns      = nvalid ? csr_src[nidx] : 0;
        const float4 nxt  = *(const float4*)(XLh + (size_t)ns * 128 + c0);

        const f16x2* xlh = (const f16x2*)&cur;
        float p = 0.f;
        #pragma unroll
        for (int j = 0; j < 4; ++j) {
            f16x2 v  = xlh[j] + xrh[j];
            f16x2 lv = __builtin_elementwise_max(v, s2 * v);
            p = __builtin_amdgcn_fdot2(lv, ath[j], p, false);
        }
        p += __shfl_xor(p, 1);
        p += __shfl_xor(p, 2);
        if (!valid) p = -INFINITY;
        float pm = fmaxf(p, __shfl_xor(p, 16));
        pm = fmaxf(pm, __shfl_xor(pm, 32));
        if (__any(pm > m + 8.f)) {
            const float mn = fmaxf(m, pm);
            const float sc = exp2f(m - mn);
            ssum *= sc;
            #pragma unroll
            for (int j = 0; j < 8; ++j) acc[j] *= sc;
            m = mn;
        }
        const float e = exp2f(p - m);
        ssum += e;
        float xlf[8];
        unpack8(cur, xlf);
        #pragma unroll
        for (int j = 0; j < 8; ++j)
            acc[j] = fmaf(e, xlf[j], acc[j]);

        cur = nxt;
        valid = nvalid;
    }
    ssum += __shfl_xor(ssum, 16);
    ssum += __shfl_xor(ssum, 32);
    #pragma unroll
    for (int j = 0; j < 8; ++j) {
        acc[j] += __shfl_xor(acc[j], 16);
        acc[j] += __shfl_xor(acc[j], 32);
    }
    if (slot == 0) {
        const float inv = 1.f / (ssum + 1e-16f);
        const float4 b0 = *(const float4*)(bias + c0);
        const float4 b1 = *(const float4*)(bias + c0 + 4);
        const float bb[8] = {b0.x, b0.y, b0.z, b0.w, b1.x, b1.y, b1.z, b1.w};
        __half2 outh[4];
        #pragma unroll
        for (int j = 0; j < 4; ++j) {
            float o0 = acc[2 * j] * inv + bb[2 * j];
            float o1 = acc[2 * j + 1] * inv + bb[2 * j + 1];
            o0 = o0 > 0.f ? o0 : expm1f(o0);
            o1 = o1 > 0.f ? o1 : expm1f(o1);
            outh[j] = __float22half2_rn(make_float2(o0, o1));
        }
        *(float4*)(H1h + (size_t)node * 128 + c0) = *(const float4*)outh;
    }
}

// ---- layer 2 fused GATv2 (H=1, C=32): 32 lanes/node, 4 edge-slots, pipelined ----
__global__ void gat2_kernel(const int* __restrict__ rowstart, const int* __restrict__ csr_src,
                            const __half* __restrict__ XLh, const __half* __restrict__ XRh,
                            const float* __restrict__ att,
                            float* __restrict__ H2)
{
    const int node = blockIdx.x * 8 + (threadIdx.x >> 5);
    if (node >= NN) return;
    const int l2   = threadIdx.x & 31;
    const int slot = l2 >> 3;
    const int q    = l2 & 7;
    const int c0   = q * 4;

    float2 xr_raw = *(const float2*)(XRh + (size_t)node * 32 + c0);
    const f16x2* xrh = (const f16x2*)&xr_raw;
    f16x2 ath[2];
    {
        const float4 a = *(const float4*)(att + c0);
        ath[0] = (f16x2){(_Float16)(a.x * LOG2E), (_Float16)(a.y * LOG2E)};
        ath[1] = (f16x2){(_Float16)(a.z * LOG2E), (_Float16)(a.w * LOG2E)};
    }
    const f16x2 s2 = {(_Float16)SLOPE, (_Float16)SLOPE};
    const int beg = rowstart[node], end = rowstart[node + 1];
    float m = -INFINITY, ssum = 0.f;
    float acc[4] = {0.f, 0.f, 0.f, 0.f};

    bool valid = (beg + slot) < end;
    int s = valid ? csr_src[beg + slot] : 0;
    float2 cur = *(const float2*)(XLh + (size_t)s * 32 + c0);

    for (int i = beg; i < end; i += 4) {
        const int nidx    = i + 4 + slot;
        const bool nvalid = nidx < end;
        const int ns      = nvalid ? csr_src[nidx] : 0;
        const float2 nxt  = *(const float2*)(XLh + (size_t)ns * 32 + c0);

        const f16x2* xlh = (const f16x2*)&cur;
        float p = 0.f;
        #pragma unroll
        for (int j = 0; j < 2; ++j) {
            f16x2 v  = xlh[j] + xrh[j];
            f16x2 lv = __builtin_elementwise_max(v, s2 * v);
            p = __builtin_amdgcn_fdot2(lv, ath[j], p, false);
        }
        p += __shfl_xor(p, 1);
        p += __shfl_xor(p, 2);
        p += __shfl_xor(p, 4);
        if (!valid) p = -INFINITY;
        float pm = fmaxf(p, __shfl_xor(p, 8));
        pm = fmaxf(pm, __shfl_xor(pm, 16));
        if (__any(pm > m + 8.f)) {
            const float mn = fmaxf(m, pm);
            const float sc = exp2f(m - mn);
            ssum *= sc;
            #pragma unroll
            for (int j = 0; j < 4; ++j) acc[j] *= sc;
            m = mn;
        }
        const float e = exp2f(p - m);
        ssum += e;
        float xlf[4];
        unpack4(cur, xlf);
        #pragma unroll
        for (int j = 0; j < 4; ++j)
            acc[j] = fmaf(e, xlf[j], acc[j]);

        cur = nxt;
        valid = nvalid;
    }
    ssum += __shfl_xor(ssum, 8);
    ssum += __shfl_xor(ssum, 16);
    #pragma unroll
    for (int j = 0; j < 4; ++j) {
        acc[j] += __shfl_xor(acc[j], 8);
        acc[j] += __shfl_xor(acc[j], 16);
    }
    if (slot == 0) {
        const float inv = 1.f / (ssum + 1e-16f);
        float4 o;
        o.x = acc[0] * inv; o.y = acc[1] * inv;
        o.z = acc[2] * inv; o.w = acc[3] * inv;
        *(float4*)(H2 + (size_t)node * 32 + c0) = o;
    }
}

// ---- mean-pool (batch sorted: run-length accumulate, then atomic flush) ----
__global__ void pool_kernel(const float* __restrict__ h2, const float* __restrict__ bias2,
                            const int* __restrict__ batch,
                            float* __restrict__ pool, float* __restrict__ cnt)
{
    const int c    = threadIdx.x & 31;
    const int slot = threadIdx.x >> 5;     // 0..7
    const int base = blockIdx.x * 256;
    const float b = bias2[c];
    float acc = 0.f, cacc = 0.f;
    int curg = -1;
    for (int i = slot; i < 256; i += 8) {
        int node = base + i;
        if (node >= NN) break;
        int g = batch[node];
        if (g != curg) {
            if (curg >= 0) {
                atomicAdd(pool + (size_t)curg * 32 + c, acc);
                if (c == 0) atomicAdd(cnt + curg, cacc);
            }
            acc = 0.f; cacc = 0.f; curg = g;
        }
        acc += h2[(size_t)node * 32 + c] + b;
        cacc += 1.f;
    }
    if (curg >= 0) {
        atomicAdd(pool + (size_t)curg * 32 + c, acc);
        if (c == 0) atomicAdd(cnt + curg, cacc);
    }
}

// ---- per-graph head MLP ----
__global__ void head_kernel(const float* __restrict__ pool, const float* __restrict__ cnt,
                            const float* __restrict__ Wh1, const float* __restrict__ bh1,
                            const float* __restrict__ Wh2, const float* __restrict__ bh2,
                            float* __restrict__ out)
{
    int g = blockIdx.x;
    int c = threadIdx.x;      // 0..63
    float partial = 0.f;
    if (c < 32) {
        float invc = 1.f / fmaxf(cnt[g], 1.f);
        float acc = bh1[c];
        #pragma unroll
        for (int k = 0; k < 32; ++k)
            acc = fmaf(pool[g * 32 + k] * invc, Wh1[k * 32 + c], acc);
        float z = fmaxf(acc, 0.f);
        partial = z * Wh2[c];
    }
    #pragma unroll
    for (int off = 32; off >= 1; off >>= 1)
        partial += __shfl_down(partial, off);
    if (c == 0) out[g] = partial + bh2[0];
}

extern "C" void kernel_launch(void* const* d_in, const int* in_sizes, int n_in,
                              void* d_out, int out_size, void* d_ws, size_t ws_size,
                              hipStream_t stream)
{
    const float* x     = (const float*)d_in[0];
    const int*   ei    = (const int*)d_in[1];
    const int*   batch = (const int*)d_in[2];
    const float* Wl1   = (const float*)d_in[3];
    const float* bl1   = (const float*)d_in[4];
    const float* Wr1   = (const float*)d_in[5];
    const float* br1   = (const float*)d_in[6];
    const float* att1  = (const float*)d_in[7];
    const float* bias1 = (const float*)d_in[8];
    const float* Wl2   = (const float*)d_in[9];
    const float* bl2   = (const float*)d_in[10];
    const float* Wr2   = (const float*)d_in[11];
    const float* br2   = (const float*)d_in[12];
    const float* att2  = (const float*)d_in[13];
    const float* bias2 = (const float*)d_in[14];
    const float* Wh1   = (const float*)d_in[15];
    const float* bh1   = (const float*)d_in[16];
    const float* Wh2   = (const float*)d_in[17];
    const float* bh2   = (const float*)d_in[18];
    const int* esrc = ei;
    const int* edst = ei + NE;

    // ---- workspace layout (bytes) ----
    char* wsb = (char*)d_ws;
    __half* xl1h = (__half*)wsb;                               // NN*128*2
    __half* xr1h = (__half*)(wsb + (size_t)NN * 128 * 2);      // NN*128*2
    __half* h1h  = xr1h;                                       // alias (per-row RAW in-wave)
    char* p2 = wsb + (size_t)NN * 128 * 4;
    __half* xl2h = (__half*)p2;                                // NN*32*2
    __half* xr2h = (__half*)(p2 + (size_t)NN * 32 * 2);        // NN*32*2
    float*  h2   = (float*)(p2 + (size_t)NN * 32 * 4);         // NN*32*4
    // zero-region: deg | cursor | pool | cnt  (single memset)
    int*    zr     = (int*)(p2 + (size_t)NN * 32 * 8);
    int*    deg    = zr;                                       // NN
    int*    cursor = zr + NN;                                  // NN
    float*  pool   = (float*)(zr + 2 * NN);                    // NG*32
    float*  cnt    = pool + (size_t)NG * 32;                   // NG
    int* rowstart  = (int*)(cnt + NG);                         // NN+1
    int* bsum      = rowstart + NN + 1;                        // 512
    int* csr_src   = bsum + 512;                               // ET
    __half* whi1   = (__half*)(csr_src + ET);                  // 16384
    __half* wlo1   = whi1 + 16384;
    __half* whi2   = wlo1 + 16384;                             // 8192
    __half* wlo2   = whi2 + 8192;

    // ---- single memset + fused init (packW1|packW2|hist) + scan + scatter ----
    hipMemsetAsync(zr, 0, (size_t)(2 * NN + NG * 32 + NG) * sizeof(int), stream);
    init_kernel<<<96 + NBH, 256, 0, stream>>>(Wl1, Wr1, whi1, wlo1,
                                              Wl2, Wr2, whi2, wlo2, edst, deg);
    scan1_kernel<<<NB1, 256, 0, stream>>>(deg, rowstart, bsum);
    scan2_kernel<<<1, 512, 0, stream>>>(bsum);
    scan3_kernel<<<NB1, 256, 0, stream>>>(rowstart, bsum);
    scatter_kernel<<<(ET + 255) / 256, 256, 0, stream>>>(esrc, edst, rowstart, cursor, csr_src);

    // ---- layer 1 ----
    t1_mfma_kernel<<<(NRT + 3) / 4, 256, 0, stream>>>(
        x, whi1, wlo1, bl1, br1, xl1h, xr1h);
    gat1_kernel<<<(NN + 3) / 4, 256, 0, stream>>>(
        rowstart, csr_src, xl1h, xr1h, att1, bias1, h1h);

    // ---- layer 2 ----
    t2_mfma_kernel<<<(NRT + 3) / 4, 256, 0, stream>>>(
        h1h, whi2, wlo2, bl2, br2, xl2h, xr2h);
    gat2_kernel<<<(NN + 7) / 8, 256, 0, stream>>>(
        rowstart, csr_src, xl2h, xr2h, att2, h2);

    // ---- pool + head ----
    pool_kernel<<<(NN + 255) / 256, 256, 0, stream>>>(h2, bias2, batch, pool, cnt);
    head_kernel<<<NG, 64, 0, stream>>>(pool, cnt, Wh1, bh1, Wh2, bh2, (float*)d_out);
}